// Round 9
// baseline (246.196 us; speedup 1.0000x reference)
//
#include <hip/hip_runtime.h>
#include <hip/hip_bf16.h>

#define KL  2304   // 48*48
#define KC  64
#define KHS 48
#define KHH 96
#define OFFY (KHS*(KL + 1))    // flat offset for (p+48,q+48); mult of 16 elems

typedef __attribute__((ext_vector_type(8))) short bf16x8;
typedef __attribute__((ext_vector_type(4))) short bf16x4;
typedef __attribute__((ext_vector_type(8))) _Float16 f16x8;
typedef __attribute__((ext_vector_type(4))) _Float16 f16x4;
typedef __attribute__((ext_vector_type(4))) float f32x4;

static __device__ inline unsigned short f2bf(float x) {
    __hip_bfloat16 h = __float2bfloat16(x);
    return *reinterpret_cast<unsigned short*>(&h);
}
static __device__ inline float bf2f(unsigned short u) {
    unsigned v = ((unsigned)u) << 16;
    return __uint_as_float(v);
}
static __device__ inline unsigned short f2h(float x) {
    _Float16 h = (_Float16)x;
    return *reinterpret_cast<unsigned short*>(&h);
}
static __device__ inline float h2f(unsigned short u) {
    _Float16 h = *reinterpret_cast<_Float16*>(&u);
    return (float)h;
}

// ---- K0' v2: downsample + |bd|^2 + mask + fp16 x-shift operands (K=192) ----
__global__ __launch_bounds__(256) void k_prep2(const float* __restrict__ f,
    const float* __restrict__ bsrc, const float* __restrict__ mask,
    float* __restrict__ nbuf, float* __restrict__ mdd,
    unsigned short* __restrict__ Ahat, unsigned short* __restrict__ Bhat)
{
    int pp = blockIdx.x*4 + (threadIdx.x >> 6);   // nb*KL total
    int c = threadIdx.x & 63;
    int p = pp % KL, bi = pp / KL;
    int y = p / KHS, x = p % KHS;
    int fy = 2*y + 1;
    unsigned short* Ap = Ahat + ((size_t)bi*KL + p)*192;
    unsigned short* Bp = Bhat + ((size_t)bi*KL + p)*192;
    float bc = 0.f;
    #pragma unroll
    for (int dxi = 0; dxi < 3; dxi++) {
        int xx = x + dxi - 1;
        float av = 0.f, bv = 0.f;
        if ((unsigned)xx < KHS) {
            int fxx = 2*xx + 1;
            size_t src = (((size_t)bi*KHH + fy)*KHH + fxx)*KC + c;
            av = f[src]; bv = bsrc[src];
        }
        if (dxi == 1) bc = bv;
        Ap[dxi*64 + c] = f2h(av);
        Bp[dxi*64 + c] = f2h(bv);
    }
    float s = bc*bc;
    #pragma unroll
    for (int off = 32; off > 0; off >>= 1) s += __shfl_down(s, off);
    if (c == 0) {
        nbuf[bi*KL + p] = s;
        mdd[bi*KL + p]  = mask[((size_t)bi*KHH + fy)*KHH + (2*x + 1)];
    }
}

// ------- K1: rnrm[q] = 1/max(sqrt(9-tap sum nb),1e-4); mm from mask --------
__global__ __launch_bounds__(256) void k_normmask(const float* __restrict__ nbuf,
    const float* __restrict__ mdd, float* __restrict__ rnrm, float* __restrict__ mm)
{
    int i = blockIdx.x*256 + threadIdx.x;   // nb*KL
    int q = i % KL, bi = i / KL;
    int v = q / KHS, u = q % KHS;
    float sn = 0.f, sm = 0.f;
    for (int dy = -1; dy <= 1; dy++) {
        int vv = v + dy; if ((unsigned)vv >= KHS) continue;
        for (int dx = -1; dx <= 1; dx++) {
            int uu = u + dx; if ((unsigned)uu >= KHS) continue;
            sn += nbuf[bi*KL + vv*KHS + uu];
            sm += mdd[bi*KL + vv*KHS + uu];
        }
    }
    rnrm[i] = 1.0f / fmaxf(sqrtf(sn), 1e-4f);
    mm[i]   = (sm == 0.0f) ? 1.0f : 0.0f;
}

// ------ MFMA GEMM (T only): C = A * B^T, fp16 in, OUTMODE {0:f32,1:bf16,2:f16}
template<int KITERS, int OUTMODE, bool INFP16>
__global__ __launch_bounds__(256) void k_mfma_bt(const unsigned short* __restrict__ A,
    const unsigned short* __restrict__ B, void* __restrict__ Cv,
    int Ncols, size_t sA, size_t sB, size_t sC, int KDIM, int nsplit, size_t psize)
{
    int flat = blockIdx.x + gridDim.x*(blockIdx.y + gridDim.y*blockIdx.z);
    int nxy = gridDim.x*gridDim.y;
    int per = (nxy*gridDim.z) >> 3;
    int g = (flat & 7)*per + (flat >> 3);
    int z = g / nxy; int r = g - z*nxy;
    int by = r / gridDim.x; int bx = r - by*gridDim.x;

    int ks = z % nsplit, bi = z / nsplit;
    int kbase = ks * KITERS * 32;
    int n0 = bx*128, m0 = by*128;
    const unsigned short* Ab = A + (size_t)bi*sA;
    const unsigned short* Bb = B + (size_t)bi*sB;
    __shared__ unsigned short As[128*32];
    __shared__ unsigned short Bs[128*32];
    int t = threadIdx.x;
    int lane = t & 63, w = t >> 6;
    int l15 = lane & 15, quad = lane >> 4;
    int swf = (l15 >> 2) & 3;
    int wm = (w >> 1)*64, wn = (w & 1)*64;
    int srow = lane >> 2;
    int ch = lane & 3;
    f32x4 acc[4][4];
    #pragma unroll
    for (int i = 0; i < 4; i++)
        #pragma unroll
        for (int j = 0; j < 4; j++) acc[i][j] = (f32x4){0.f,0.f,0.f,0.f};

    for (int kk = 0; kk < KITERS; kk++) {
        int k0 = kbase + kk*32;
        #pragma unroll
        for (int i = 0; i < 2; i++) {
            int rbase = w*32 + i*16;
            int r2 = rbase + srow;
            int cs = (ch ^ ((r2 >> 2) & 3))*8;
            const unsigned short* ga = &Ab[(size_t)(m0 + r2)*KDIM + k0 + cs];
            __builtin_amdgcn_global_load_lds(
                (const __attribute__((address_space(1))) void*)ga,
                (__attribute__((address_space(3))) void*)&As[rbase*32], 16, 0, 0);
            const unsigned short* gb = &Bb[(size_t)(n0 + r2)*KDIM + k0 + cs];
            __builtin_amdgcn_global_load_lds(
                (const __attribute__((address_space(1))) void*)gb,
                (__attribute__((address_space(3))) void*)&Bs[rbase*32], 16, 0, 0);
        }
        __syncthreads();
        if (INFP16) {
            f16x8 af[4], bfr[4];
            #pragma unroll
            for (int mi = 0; mi < 4; mi++)
                af[mi] = *(const f16x8*)&As[(wm + mi*16 + l15)*32 + ((quad ^ swf)*8)];
            #pragma unroll
            for (int ni = 0; ni < 4; ni++)
                bfr[ni] = *(const f16x8*)&Bs[(wn + ni*16 + l15)*32 + ((quad ^ swf)*8)];
            #pragma unroll
            for (int mi = 0; mi < 4; mi++)
                #pragma unroll
                for (int ni = 0; ni < 4; ni++)
                    acc[mi][ni] = __builtin_amdgcn_mfma_f32_16x16x32_f16(
                        af[mi], bfr[ni], acc[mi][ni], 0, 0, 0);
        } else {
            bf16x8 af[4], bfr[4];
            #pragma unroll
            for (int mi = 0; mi < 4; mi++)
                af[mi] = *(const bf16x8*)&As[(wm + mi*16 + l15)*32 + ((quad ^ swf)*8)];
            #pragma unroll
            for (int ni = 0; ni < 4; ni++)
                bfr[ni] = *(const bf16x8*)&Bs[(wn + ni*16 + l15)*32 + ((quad ^ swf)*8)];
            #pragma unroll
            for (int mi = 0; mi < 4; mi++)
                #pragma unroll
                for (int ni = 0; ni < 4; ni++)
                    acc[mi][ni] = __builtin_amdgcn_mfma_f32_16x16x32_bf16(
                        af[mi], bfr[ni], acc[mi][ni], 0, 0, 0);
        }
        __syncthreads();
    }
    if (OUTMODE == 1 || OUTMODE == 2) {
        unsigned short* Cb = (unsigned short*)Cv + (size_t)ks*psize + (size_t)bi*sC;
        #pragma unroll
        for (int mi = 0; mi < 4; mi++)
            #pragma unroll
            for (int ni = 0; ni < 4; ni++) {
                int col = n0 + wn + ni*16 + l15;
                #pragma unroll
                for (int r2 = 0; r2 < 4; r2++) {
                    int row = m0 + wm + mi*16 + quad*4 + r2;
                    Cb[(size_t)row*Ncols + col] = (OUTMODE == 1)
                        ? f2bf(acc[mi][ni][r2]) : f2h(acc[mi][ni][r2]);
                }
            }
    } else {
        float* Cb = (float*)Cv + (size_t)ks*psize + (size_t)bi*sC;
        #pragma unroll
        for (int mi = 0; mi < 4; mi++)
            #pragma unroll
            for (int ni = 0; ni < 4; ni++) {
                int col = n0 + wn + ni*16 + l15;
                #pragma unroll
                for (int r2 = 0; r2 < 4; r2++) {
                    int row = m0 + wm + mi*16 + quad*4 + r2;
                    Cb[(size_t)row*Ncols + col] = acc[mi][ni][r2];
                }
            }
    }
}

// ====== k_p8 v6 (FROZEN): R3-v2 schedule + chunk swizzle, 59.6us measured ===
#define KP_NT 24
#define STGA4(tt, j) do {                                                      \
    __builtin_amdgcn_global_load_lds(                                          \
        (const __attribute__((address_space(1))) void*)(gA + (size_t)(j)*128*2304 + (size_t)(tt)*32), \
        (__attribute__((address_space(3))) void*)&Atile[(tt)&3][((j)*128 + (w<<4))*32], 16, 0, 0); \
} while (0)
#define STGB4(tt, j) do {                                                      \
    __builtin_amdgcn_global_load_lds(                                          \
        (const __attribute__((address_space(1))) void*)(gB + (size_t)(j)*128*2304 + (size_t)(tt)*32), \
        (__attribute__((address_space(3))) void*)&Btile[(tt)&3][((j)*128 + (w<<4))*32], 16, 0, 0); \
} while (0)

#define MFMA_B(a, b, c) __builtin_amdgcn_mfma_f32_16x16x32_bf16(a, b, c, 0, 0, 0)

#define KT_BODY(kt, BVU, BVF) do {                                             \
    const unsigned short* At = &Atile[(kt) & 3][0];                            \
    /* ---- E(kt) ---- */                                                      \
    __builtin_amdgcn_s_barrier();                                              \
    _Pragma("unroll")                                                          \
    for (int i = 0; i < 4; i++)                                                \
        af1[i] = *(const bf16x8*)&At[aOff + 2048 + i*512];                     \
    if ((kt) + 3 < KP_NT) { STGA4((kt)+3, 0); STGA4((kt)+3, 1); }              \
    __builtin_amdgcn_s_setprio(1);                                             \
    _Pragma("unroll")                                                          \
    for (int mi = 0; mi < 4; mi++)                                             \
        _Pragma("unroll")                                                      \
        for (int ni = 0; ni < 4; ni++)                                         \
            acc[mi][ni] = MFMA_B(af0[mi], BVU[ni], acc[mi][ni]);               \
    __builtin_amdgcn_s_setprio(0);                                             \
    /* ---- L(kt) ---- */                                                      \
    __builtin_amdgcn_s_barrier();                                              \
    if ((kt) < KP_NT-1) {                                                      \
        if ((kt) <= KP_NT-4)      asm volatile("s_waitcnt vmcnt(6)" ::: "memory"); \
        else if ((kt) == KP_NT-3) asm volatile("s_waitcnt vmcnt(4)" ::: "memory"); \
        else                      asm volatile("s_waitcnt vmcnt(0)" ::: "memory"); \
        __builtin_amdgcn_sched_barrier(0);                                     \
        const unsigned short* An = &Atile[((kt)+1) & 3][0];                    \
        const unsigned short* Bn = &Btile[((kt)+1) & 3][0];                    \
        _Pragma("unroll")                                                      \
        for (int i = 0; i < 4; i++)                                            \
            af0[i] = *(const bf16x8*)&An[aOff + i*512];                        \
        _Pragma("unroll")                                                      \
        for (int ni = 0; ni < 4; ni++)                                         \
            BVF[ni] = *(const bf16x8*)&Bn[bOff + ni*512];                      \
    }                                                                          \
    if ((kt) + 3 < KP_NT) { STGB4((kt)+3, 0); STGB4((kt)+3, 1); }              \
    __builtin_amdgcn_s_setprio(1);                                             \
    _Pragma("unroll")                                                          \
    for (int mi = 0; mi < 4; mi++)                                             \
        _Pragma("unroll")                                                      \
        for (int ni = 0; ni < 4; ni++)                                         \
            acc[4+mi][ni] = MFMA_B(af1[mi], BVU[ni], acc[4+mi][ni]);           \
    __builtin_amdgcn_s_setprio(0);                                             \
} while (0)

__global__ __launch_bounds__(512, 2) void k_p8(
    const unsigned short* __restrict__ A,   // Ybf: [bi][2304][2304] bf16
    const unsigned short* __restrict__ B,   // Rt : [bi][1024][2304] bf16
    unsigned short* __restrict__ C,         // partials: ks*psize + bi*2304*1024
    size_t psize)
{
    __shared__ unsigned short Atile[4][8192];   // 4 x 256 x 32 (16 KiB each)
    __shared__ unsigned short Btile[4][8192];

    // bijective XCD swizzle (m204, any nwg)
    int flat = blockIdx.x + gridDim.x*(blockIdx.y + gridDim.y*blockIdx.z);
    int nwg = gridDim.x*gridDim.y*gridDim.z;
    int qq = nwg >> 3, rr8 = nwg & 7;
    int xcd = flat & 7, sub = flat >> 3;
    int g = (xcd < rr8 ? xcd*(qq+1) : rr8*(qq+1) + (xcd - rr8)*qq) + sub;
    int nxy = gridDim.x*gridDim.y;              // 36
    int z = g / nxy; int rg = g - z*nxy;
    int by = rg / gridDim.x; int bx = rg - by*gridDim.x;

    int ks = z % 3, bi = z / 3;
    int kbase = ks * 768;
    int m0 = by * 256, n0 = bx * 256;
    const unsigned short* Ab = A + (size_t)bi * (2304ull*2304);
    const unsigned short* Bb = B + (size_t)bi * (1024ull*2304);

    int t = threadIdx.x;
    int w = t >> 6, lane = t & 63;
    int wr = w >> 2, wc = w & 3;
    int l15 = lane & 15, quad = lane >> 4;

    // staging source: row = t>>2, phys chunk (t&3) holds global chunk
    // (t&3) ^ ((row>>1)&3) = (t&3) ^ ((t>>3)&3)   (pre-swizzled global, G21)
    int scol = ((t & 3) ^ ((t >> 3) & 3))*8;
    const unsigned short* gA = Ab + (size_t)(m0 + (t >> 2))*2304 + kbase + scol;
    const unsigned short* gB = Bb + (size_t)(n0 + (t >> 2))*2304 + kbase + scol;

    // frag read offsets (elements): row*32 + (quad ^ ((row>>1)&3))*8
    int csw = (quad ^ ((l15 >> 1) & 3))*8;
    int aOff = (wr*128 + l15)*32 + csw;
    int bOff = (wc*64  + l15)*32 + csw;

    f32x4 acc[8][4];
    #pragma unroll
    for (int mi = 0; mi < 8; mi++)
        #pragma unroll
        for (int ni = 0; ni < 4; ni++) acc[mi][ni] = (f32x4){0.f,0.f,0.f,0.f};

    // prologue: stage tiles 0,1,2 (12 ops); tile0 ready at vmcnt(8)
    #pragma unroll
    for (int tt = 0; tt < 3; tt++) {
        STGA4(tt, 0); STGA4(tt, 1);
        STGB4(tt, 0); STGB4(tt, 1);
    }
    asm volatile("s_waitcnt vmcnt(8)" ::: "memory");
    __builtin_amdgcn_s_barrier();

    bf16x8 af0[4], af1[4], bvA[4], bvB[4];
    // S1(0): af0 + bvA from buf0
    #pragma unroll
    for (int i = 0; i < 4; i++)
        af0[i] = *(const bf16x8*)&Atile[0][aOff + i*512];
    #pragma unroll
    for (int ni = 0; ni < 4; ni++)
        bvA[ni] = *(const bf16x8*)&Btile[0][bOff + ni*512];

    #pragma unroll 1
    for (int ktp = 0; ktp < KP_NT/2; ktp++) {
        int kt0 = ktp*2;
        KT_BODY(kt0,     bvA, bvB);   // even tile: use bvA, fill bvB
        KT_BODY(kt0 + 1, bvB, bvA);   // odd tile:  use bvB, fill bvA
    }

    // epilogue: bf16 partial write
    unsigned short* Cb = C + (size_t)ks*psize + (size_t)bi*(2304ull*1024);
    #pragma unroll
    for (int mi = 0; mi < 8; mi++)
        #pragma unroll
        for (int ni = 0; ni < 4; ni++) {
            int col = n0 + wc*64 + ni*16 + l15;
            int rowb = m0 + wr*128 + mi*16 + quad*4;
            #pragma unroll
            for (int r = 0; r < 4; r++)
                Cb[(size_t)(rowb + r)*1024 + col] = f2bf(acc[mi][ni][r]);
        }
}

// ------ K3b v5: y-diag 3-tap * rnrm + fuse1, fp16; 16 rows/block ------------
// Stages 18 rows for 16 outputs (halo 1.125x, was 1.25x); output accumulator
// form (out[rr] += g0/g1/g2) is bit-identical to the h0+h1+h2 ordering.
__global__ __launch_bounds__(256) void k_fuse_a2(const unsigned short* __restrict__ T,
    const float* __restrict__ rnrm, const float* __restrict__ fw,
    unsigned short* __restrict__ Y1)
{
    __shared__ float Sl[18][280];
    int flat = blockIdx.x + 9*(blockIdx.y + 144*blockIdx.z);
    int nwg = 1296*gridDim.z;          // %8 == 0 for nb in {1,2,4}
    int cpx = nwg >> 3;
    int g = (flat & 7)*cpx + (flat >> 3);
    int bi = g / 1296; int rem = g - bi*1296;
    int by = rem / 9;  int qt = rem - by*9;

    int p0 = by*16, q0 = qt*256;
    const unsigned short* Tb = T + (size_t)bi*KL*KL;
    const float* rn = rnrm + bi*KL;
    int t = threadIdx.x;
    bool edge = (qt == 0) | (qt == 8);
    if (!edge) {
        for (int idx = t; idx < 18*34; idx += 256) {
            int r = idx / 34, j = idx - r*34;
            int pp = p0 - 1 + r;
            int qq0 = q0 - 8 + j*8;
            float s[8];
            #pragma unroll
            for (int k = 0; k < 8; k++) s[k] = 0.f;
            if ((unsigned)pp < KL) {
                size_t base = (size_t)pp*KL + qq0;
                bool bm = (pp >= KHS), bp = (pp < KL - KHS);
                size_t offm = bm ? (size_t)OFFY : 0;
                size_t offp = bp ? (size_t)OFFY : 0;
                float fm = bm ? 1.f : 0.f, fp2 = bp ? 1.f : 0.f;
                f16x8 v0 = *(const f16x8*)&Tb[base];
                f16x8 vm = *(const f16x8*)&Tb[base - offm];
                f16x8 vp = *(const f16x8*)&Tb[base + offp];
                #pragma unroll
                for (int k = 0; k < 8; k++)
                    s[k] = ((float)v0[k] + fm*(float)vm[k] + fp2*(float)vp[k]) * rn[qq0 + k];
            }
            #pragma unroll
            for (int k = 0; k < 8; k++) Sl[r][j*8 + k] = s[k];
        }
    } else {
        for (int idx = t; idx < 18*272; idx += 256) {
            int r = idx / 272, c = idx - r*272;
            int pp = p0 - 1 + r, qq = q0 - 8 + c;
            float s = 0.f;
            if ((unsigned)pp < KL && (unsigned)qq < KL) {
                size_t base = (size_t)pp*KL + qq;
                float acc = h2f(Tb[base]);
                if (pp >= KHS && qq >= KHS)         acc += h2f(Tb[base - OFFY]);
                if (pp < KL - KHS && qq < KL - KHS) acc += h2f(Tb[base + OFFY]);
                s = acc * rn[qq];
            }
            Sl[r][c] = s;
        }
    }
    __syncthreads();
    float w[9];
    #pragma unroll
    for (int i = 0; i < 9; i++) w[i] = fw[i];
    int q = q0 + t;
    float outv[16];
    #pragma unroll
    for (int rr = 0; rr < 16; rr++) outv[rr] = 0.f;
    #pragma unroll
    for (int r = 0; r < 18; r++) {
        float s0 = Sl[r][t+7], s1 = Sl[r][t+8], s2 = Sl[r][t+9];
        float g0 = w[0]*s0 + w[1]*s1 + w[2]*s2;
        float g1 = w[3]*s0 + w[4]*s1 + w[5]*s2;
        float g2 = w[6]*s0 + w[7]*s1 + w[8]*s2;
        if (r < 16)            outv[r]     += g0;
        if (r >= 1 && r <= 16) outv[r - 1] += g1;
        if (r >= 2)            outv[r - 2] += g2;
    }
    #pragma unroll
    for (int rr = 0; rr < 16; rr++) {
        Y1[((size_t)bi*KL + p0 + rr)*KL + q] = f2h(outv[rr]);
    }
}

// ------ K5 v7: fuse conv #2 + softmax -> bf16; 8 rows/block, 512 thr --------
// Stages 10 rows for 8 outputs (halo 1.25x, was 1.5x); 1 warp per row,
// shuffle-only reduction.
__global__ __launch_bounds__(512) void k_fuse_b(const unsigned short* __restrict__ Y1,
    const float* __restrict__ fw, const float* __restrict__ mm,
    unsigned short* __restrict__ Ybf)
{
    __shared__ float rowb[10][KL];   // 92160 B
    int blk = blockIdx.x;            // nb*288
    int tp0 = (blk % 288)*8;
    int bi  = blk / 288;
    int t = threadIdx.x;
    const unsigned short* Yb = Y1 + (size_t)bi*KL*KL;
    for (int idx = t; idx < 10*(KL/8); idx += 512) {
        int a = idx / (KL/8), i = idx - a*(KL/8);
        int t2 = tp0 - 1 + a;
        if ((unsigned)t2 < KL) {
            int pr = (t2 % KHS)*KHS + t2/KHS;
            f16x8 v = *(const f16x8*)&Yb[(size_t)pr*KL + i*8];
            #pragma unroll
            for (int j = 0; j < 8; j++) rowb[a][i*8 + j] = (float)v[j];
        } else {
            #pragma unroll
            for (int j = 0; j < 8; j++) rowb[a][i*8 + j] = 0.f;
        }
    }
    float w9[9];
    #pragma unroll
    for (int i = 0; i < 9; i++) w9[i] = fw[i];
    __syncthreads();
    int w = t >> 6, lane = t & 63;
    int tp = tp0 + w;
    int x = tp / KHS, y = tp - x*KHS;   // tp = x*48 + y
    int p = y*KHS + x;
    const float* mmb = mm + bi*KL;
    float vals[36];
    float lmax = -1e30f;
    #pragma unroll
    for (int i = 0; i < 36; i++) {
        int q = lane + i*64;
        int qm = (q >= KHS)      ? q - KHS : 2255 + q;
        int qp = (q <= KL-1-KHS) ? q + KHS : q - 2255;
        float fm = (q != 0)    ? 1.f : 0.f;
        float fp = (q != KL-1) ? 1.f : 0.f;
        float am = w9[0]*rowb[w][qm] + w9[3]*rowb[w+1][qm] + w9[6]*rowb[w+2][qm];
        float a0 = w9[1]*rowb[w][q]  + w9[4]*rowb[w+1][q]  + w9[7]*rowb[w+2][q];
        float ap = w9[2]*rowb[w][qp] + w9[5]*rowb[w+1][qp] + w9[8]*rowb[w+2][qp];
        float val = (fm*am + a0 + fp*ap) * mmb[q] * 10.0f;
        vals[i] = val;
        lmax = fmaxf(lmax, val);
    }
    #pragma unroll
    for (int off = 32; off > 0; off >>= 1) lmax = fmaxf(lmax, __shfl_down(lmax, off));
    lmax = __shfl(lmax, 0);
    float lsum = 0.f;
    #pragma unroll
    for (int i = 0; i < 36; i++) {
        float e = __expf(vals[i] - lmax);
        vals[i] = e;
        lsum += e;
    }
    #pragma unroll
    for (int off = 32; off > 0; off >>= 1) lsum += __shfl_down(lsum, off);
    lsum = __shfl(lsum, 0);
    float inv = 1.0f / lsum;
    unsigned short* orow = Ybf + ((size_t)bi*KL + p)*KL;
    #pragma unroll
    for (int i = 0; i < 36; i++) {
        int q = lane + i*64;
        orow[q] = f2bf(vals[i]*inv*mmb[q]);
    }
}

// ---- KR v2: Rt[n][k] bf16 via LDS transpose (coalesced reads + writes) -----
__global__ __launch_bounds__(256) void k_buildRt(const float* __restrict__ bsrc,
    unsigned short* __restrict__ Rt)
{
    __shared__ unsigned short Ls[2][48][65];
    int blk = blockIdx.x;             // nb*384: vb fastest, then jj, then bi
    int vb = blk % 24;
    int jj = (blk / 24) % 16;
    int bi = blk / 384;
    int ky = jj >> 2, kx = jj & 3;
    int v0 = vb*2;
    int t = threadIdx.x;
    int c = t & 63, u4 = t >> 6;

    #pragma unroll
    for (int vv = 0; vv < 2; vv++) {
        int ry = 2*(v0 + vv) + ky - 1;
        bool ryok = (unsigned)ry < KHH;
        const float* brow = bsrc + (((size_t)bi*KHH + (ryok ? ry : 0))*KHH)*KC;
        #pragma unroll
        for (int j = 0; j < 12; j++) {
            int u = u4*12 + j;
            int rx = 2*u + kx - 1;
            float val = 0.f;
            if (ryok && (unsigned)rx < KHH)
                val = brow[(size_t)rx*KC + c];
            Ls[vv][u][c] = f2bf(val);
        }
    }
    __syncthreads();

    int cn = t >> 2, part = t & 3;
    unsigned short* orow = Rt + ((size_t)bi*1024 + jj*64 + cn)*KL + vb*96;
    #pragma unroll
    for (int ch = 0; ch < 3; ch++) {
        int ql = part*24 + ch*8;          // 8-aligned, never straddles vv
        int vv = ql / 48;
        int ub = ql - vv*48;
        bf16x8 v8;
        #pragma unroll
        for (int j = 0; j < 8; j++)
            v8[j] = (short)Ls[vv][ub + j][cn];
        *(bf16x8*)&orow[ql] = v8;
    }
}

// -- K8 v2: overlap-add over 3 bf16 partials, 8 ch/thread, bf16x8 loads ------
__global__ __launch_bounds__(256) void k_overlap(const unsigned short* __restrict__ P,
    float* __restrict__ out, size_t psize)
{
    size_t gid = (size_t)blockIdx.x*256 + threadIdx.x;   // nb*96*96*8
    int c8 = (int)(gid & 7)*8;
    size_t r = gid >> 3;
    int ix = (int)(r % KHH); r /= KHH;
    int iy = (int)(r % KHH);
    int bi = (int)(r / KHH);
    float acc[8];
    #pragma unroll
    for (int j = 0; j < 8; j++) acc[j] = 0.f;
    #pragma unroll
    for (int sy = 0; sy < 2; sy++) {
        int ky = (iy & 1) ? (sy*2) : (sy*2 + 1);
        int yp = (iy + 1 - ky) >> 1;
        if ((unsigned)yp >= KHS) continue;
        #pragma unroll
        for (int sx = 0; sx < 2; sx++) {
            int kx = (ix & 1) ? (sx*2) : (sx*2 + 1);
            int xp = (ix + 1 - kx) >> 1;
            if ((unsigned)xp >= KHS) continue;
            size_t idx = (((size_t)bi*KL + yp*KHS + xp)*16 + (ky*4 + kx))*64 + c8;
            #pragma unroll
            for (int s = 0; s < 3; s++) {
                bf16x8 v = *(const bf16x8*)&P[idx + s*psize];
                #pragma unroll
                for (int j = 0; j < 8; j++)
                    acc[j] += bf2f((unsigned short)v[j]);
            }
        }
    }
    float* op = &out[(((size_t)bi*KHH + iy)*KHH + ix)*KC + c8];
    f32x4 o0 = (f32x4){acc[0], acc[1], acc[2], acc[3]} * 0.25f;
    f32x4 o1 = (f32x4){acc[4], acc[5], acc[6], acc[7]} * 0.25f;
    *(f32x4*)&op[0] = o0;
    *(f32x4*)&op[4] = o1;
}

extern "C" void kernel_launch(void* const* d_in, const int* in_sizes, int n_in,
                              void* d_out, int out_size, void* d_ws, size_t ws_size,
                              hipStream_t stream)
{
    const float* f    = (const float*)d_in[0];
    const float* b    = (const float*)d_in[1];
    const float* mask = (const float*)d_in[2];
    const float* fw   = (const float*)d_in[3];
    float* out = (float*)d_out;

    auto need = [](int nbc) -> size_t {
        return (size_t)nbc * (2ull*KL*KC + 4ull*KL + 2ull*(size_t)KL*KL) * 4ull;
    };
    int nbc = 4;
    if (need(nbc) > ws_size) nbc = 2;
    if (need(nbc) > ws_size) nbc = 1;

    for (int bi0 = 0; bi0 < 4; bi0 += nbc) {
        int nb = (4 - bi0 < nbc) ? (4 - bi0) : nbc;
        const float* fc = f    + (size_t)bi0*KHH*KHH*KC;
        const float* bc = b    + (size_t)bi0*KHH*KHH*KC;
        const float* mc = mask + (size_t)bi0*KHH*KHH;
        float* outc = out + (size_t)bi0*KHH*KHH*KC;

        float* w    = (float*)d_ws;
        float* nbuf = w;  w += (size_t)nbc*KL;
        float* mdd  = w;  w += (size_t)nbc*KL;
        float* rnrm = w;  w += (size_t)nbc*KL;
        float* mmb  = w;  w += (size_t)nbc*KL;
        float* bufA = w;  w += (size_t)nbc*KL*KL;
        float* bufB = w;
        // lifetimes:
        //  bufB: [Ahat|Bhat] (fp16) -> Y1 (fp16) -> P0..P2 (bf16, 3 partials)
        //  bufA: T (fp16) -> [Ybf bf16 | Rt bf16]
        unsigned short* Ahat = (unsigned short*)bufB;
        unsigned short* Bhat = Ahat + (size_t)nbc*KL*192;
        unsigned short* Tbuf = (unsigned short*)bufA;
        unsigned short* Y1   = (unsigned short*)bufB;
        unsigned short* Ybf = (unsigned short*)bufA;
        unsigned short* Rtb = Ybf + (size_t)nbc*KL*KL;
        unsigned short* Pbuf = (unsigned short*)bufB;
        size_t psize = (size_t)nbc*KL*1024;   // one split-K partial (elements)

        k_prep2     <<<nb*KL/4, 256, 0, stream>>>(fc, bc, mc, nbuf, mdd, Ahat, Bhat);
        k_normmask  <<<(nb*KL)/256, 256, 0, stream>>>(nbuf, mdd, rnrm, mmb);
        // T = Ahat * Bhat^T  (K=192 fp16 single-segment, fp16 out)
        k_mfma_bt<6,2,true><<<dim3(18, 18, nb), 256, 0, stream>>>(
            Ahat, Bhat, Tbuf, KL, (size_t)KL*192, (size_t)KL*192, (size_t)KL*KL,
            192, 1, 0);
        // y-diag 3-tap * rnrm + fuse1: T fp16 (bufA) -> Y1 fp16 (bufB), 16 rows/blk
        k_fuse_a2   <<<dim3(9, 144, nb), 256, 0, stream>>>(Tbuf, rnrm, fw, Y1);
        // fuse2 + softmax: Y1 fp16 (bufB) -> Ybf bf16 (bufA), 8 rows/blk
        k_fuse_b    <<<nb*288, 512, 0, stream>>>(Y1, fw, mmb, Ybf);
        // Rt build via LDS transpose (coalesced)
        k_buildRt   <<<nb*384, 256, 0, stream>>>(bc, Rtb);
        // P = Ybf * Rt^T (K=2304 bf16, split-K=3, bf16 partials P0..P2) [FROZEN]
        k_p8<<<dim3(4, 9, nb*3), 512, 0, stream>>>(Ybf, Rtb, Pbuf, psize);
        // overlap-add, 8 channels/thread
        k_overlap   <<<nb*288, 256, 0, stream>>>(Pbuf, outc, psize);
    }
}

// Round 10
// 242.216 us; speedup vs baseline: 1.0164x; 1.0164x over previous
//
#include <hip/hip_runtime.h>
#include <hip/hip_bf16.h>

#define KL  2304   // 48*48
#define KC  64
#define KHS 48
#define KHH 96
#define OFFY (KHS*(KL + 1))    // flat offset for (p+48,q+48); mult of 16 elems

typedef __attribute__((ext_vector_type(8))) short bf16x8;
typedef __attribute__((ext_vector_type(4))) short bf16x4;
typedef __attribute__((ext_vector_type(8))) _Float16 f16x8;
typedef __attribute__((ext_vector_type(4))) _Float16 f16x4;
typedef __attribute__((ext_vector_type(4))) float f32x4;

static __device__ inline unsigned short f2bf(float x) {
    __hip_bfloat16 h = __float2bfloat16(x);
    return *reinterpret_cast<unsigned short*>(&h);
}
static __device__ inline float bf2f(unsigned short u) {
    unsigned v = ((unsigned)u) << 16;
    return __uint_as_float(v);
}
static __device__ inline unsigned short f2h(float x) {
    _Float16 h = (_Float16)x;
    return *reinterpret_cast<unsigned short*>(&h);
}
static __device__ inline float h2f(unsigned short u) {
    _Float16 h = *reinterpret_cast<_Float16*>(&u);
    return (float)h;
}

// ---- K0' v2: downsample + |bd|^2 + mask + fp16 x-shift operands (K=192) ----
__global__ __launch_bounds__(256) void k_prep2(const float* __restrict__ f,
    const float* __restrict__ bsrc, const float* __restrict__ mask,
    float* __restrict__ nbuf, float* __restrict__ mdd,
    unsigned short* __restrict__ Ahat, unsigned short* __restrict__ Bhat)
{
    int pp = blockIdx.x*4 + (threadIdx.x >> 6);   // nb*KL total
    int c = threadIdx.x & 63;
    int p = pp % KL, bi = pp / KL;
    int y = p / KHS, x = p % KHS;
    int fy = 2*y + 1;
    unsigned short* Ap = Ahat + ((size_t)bi*KL + p)*192;
    unsigned short* Bp = Bhat + ((size_t)bi*KL + p)*192;
    float bc = 0.f;
    #pragma unroll
    for (int dxi = 0; dxi < 3; dxi++) {
        int xx = x + dxi - 1;
        float av = 0.f, bv = 0.f;
        if ((unsigned)xx < KHS) {
            int fxx = 2*xx + 1;
            size_t src = (((size_t)bi*KHH + fy)*KHH + fxx)*KC + c;
            av = f[src]; bv = bsrc[src];
        }
        if (dxi == 1) bc = bv;
        Ap[dxi*64 + c] = f2h(av);
        Bp[dxi*64 + c] = f2h(bv);
    }
    float s = bc*bc;
    #pragma unroll
    for (int off = 32; off > 0; off >>= 1) s += __shfl_down(s, off);
    if (c == 0) {
        nbuf[bi*KL + p] = s;
        mdd[bi*KL + p]  = mask[((size_t)bi*KHH + fy)*KHH + (2*x + 1)];
    }
}

// ------- K1: rnrm[q] = 1/max(sqrt(9-tap sum nb),1e-4); mm from mask --------
__global__ __launch_bounds__(256) void k_normmask(const float* __restrict__ nbuf,
    const float* __restrict__ mdd, float* __restrict__ rnrm, float* __restrict__ mm)
{
    int i = blockIdx.x*256 + threadIdx.x;   // nb*KL
    int q = i % KL, bi = i / KL;
    int v = q / KHS, u = q % KHS;
    float sn = 0.f, sm = 0.f;
    for (int dy = -1; dy <= 1; dy++) {
        int vv = v + dy; if ((unsigned)vv >= KHS) continue;
        for (int dx = -1; dx <= 1; dx++) {
            int uu = u + dx; if ((unsigned)uu >= KHS) continue;
            sn += nbuf[bi*KL + vv*KHS + uu];
            sm += mdd[bi*KL + vv*KHS + uu];
        }
    }
    rnrm[i] = 1.0f / fmaxf(sqrtf(sn), 1e-4f);
    mm[i]   = (sm == 0.0f) ? 1.0f : 0.0f;
}

// ------ MFMA GEMM (T only): C = A * B^T, fp16 in, OUTMODE {0:f32,1:bf16,2:f16}
template<int KITERS, int OUTMODE, bool INFP16>
__global__ __launch_bounds__(256) void k_mfma_bt(const unsigned short* __restrict__ A,
    const unsigned short* __restrict__ B, void* __restrict__ Cv,
    int Ncols, size_t sA, size_t sB, size_t sC, int KDIM, int nsplit, size_t psize)
{
    int flat = blockIdx.x + gridDim.x*(blockIdx.y + gridDim.y*blockIdx.z);
    int nxy = gridDim.x*gridDim.y;
    int per = (nxy*gridDim.z) >> 3;
    int g = (flat & 7)*per + (flat >> 3);
    int z = g / nxy; int r = g - z*nxy;
    int by = r / gridDim.x; int bx = r - by*gridDim.x;

    int ks = z % nsplit, bi = z / nsplit;
    int kbase = ks * KITERS * 32;
    int n0 = bx*128, m0 = by*128;
    const unsigned short* Ab = A + (size_t)bi*sA;
    const unsigned short* Bb = B + (size_t)bi*sB;
    __shared__ unsigned short As[128*32];
    __shared__ unsigned short Bs[128*32];
    int t = threadIdx.x;
    int lane = t & 63, w = t >> 6;
    int l15 = lane & 15, quad = lane >> 4;
    int swf = (l15 >> 2) & 3;
    int wm = (w >> 1)*64, wn = (w & 1)*64;
    int srow = lane >> 2;
    int ch = lane & 3;
    f32x4 acc[4][4];
    #pragma unroll
    for (int i = 0; i < 4; i++)
        #pragma unroll
        for (int j = 0; j < 4; j++) acc[i][j] = (f32x4){0.f,0.f,0.f,0.f};

    for (int kk = 0; kk < KITERS; kk++) {
        int k0 = kbase + kk*32;
        #pragma unroll
        for (int i = 0; i < 2; i++) {
            int rbase = w*32 + i*16;
            int r2 = rbase + srow;
            int cs = (ch ^ ((r2 >> 2) & 3))*8;
            const unsigned short* ga = &Ab[(size_t)(m0 + r2)*KDIM + k0 + cs];
            __builtin_amdgcn_global_load_lds(
                (const __attribute__((address_space(1))) void*)ga,
                (__attribute__((address_space(3))) void*)&As[rbase*32], 16, 0, 0);
            const unsigned short* gb = &Bb[(size_t)(n0 + r2)*KDIM + k0 + cs];
            __builtin_amdgcn_global_load_lds(
                (const __attribute__((address_space(1))) void*)gb,
                (__attribute__((address_space(3))) void*)&Bs[rbase*32], 16, 0, 0);
        }
        __syncthreads();
        if (INFP16) {
            f16x8 af[4], bfr[4];
            #pragma unroll
            for (int mi = 0; mi < 4; mi++)
                af[mi] = *(const f16x8*)&As[(wm + mi*16 + l15)*32 + ((quad ^ swf)*8)];
            #pragma unroll
            for (int ni = 0; ni < 4; ni++)
                bfr[ni] = *(const f16x8*)&Bs[(wn + ni*16 + l15)*32 + ((quad ^ swf)*8)];
            #pragma unroll
            for (int mi = 0; mi < 4; mi++)
                #pragma unroll
                for (int ni = 0; ni < 4; ni++)
                    acc[mi][ni] = __builtin_amdgcn_mfma_f32_16x16x32_f16(
                        af[mi], bfr[ni], acc[mi][ni], 0, 0, 0);
        } else {
            bf16x8 af[4], bfr[4];
            #pragma unroll
            for (int mi = 0; mi < 4; mi++)
                af[mi] = *(const bf16x8*)&As[(wm + mi*16 + l15)*32 + ((quad ^ swf)*8)];
            #pragma unroll
            for (int ni = 0; ni < 4; ni++)
                bfr[ni] = *(const bf16x8*)&Bs[(wn + ni*16 + l15)*32 + ((quad ^ swf)*8)];
            #pragma unroll
            for (int mi = 0; mi < 4; mi++)
                #pragma unroll
                for (int ni = 0; ni < 4; ni++)
                    acc[mi][ni] = __builtin_amdgcn_mfma_f32_16x16x32_bf16(
                        af[mi], bfr[ni], acc[mi][ni], 0, 0, 0);
        }
        __syncthreads();
    }
    if (OUTMODE == 1 || OUTMODE == 2) {
        unsigned short* Cb = (unsigned short*)Cv + (size_t)ks*psize + (size_t)bi*sC;
        #pragma unroll
        for (int mi = 0; mi < 4; mi++)
            #pragma unroll
            for (int ni = 0; ni < 4; ni++) {
                int col = n0 + wn + ni*16 + l15;
                #pragma unroll
                for (int r2 = 0; r2 < 4; r2++) {
                    int row = m0 + wm + mi*16 + quad*4 + r2;
                    Cb[(size_t)row*Ncols + col] = (OUTMODE == 1)
                        ? f2bf(acc[mi][ni][r2]) : f2h(acc[mi][ni][r2]);
                }
            }
    } else {
        float* Cb = (float*)Cv + (size_t)ks*psize + (size_t)bi*sC;
        #pragma unroll
        for (int mi = 0; mi < 4; mi++)
            #pragma unroll
            for (int ni = 0; ni < 4; ni++) {
                int col = n0 + wn + ni*16 + l15;
                #pragma unroll
                for (int r2 = 0; r2 < 4; r2++) {
                    int row = m0 + wm + mi*16 + quad*4 + r2;
                    Cb[(size_t)row*Ncols + col] = acc[mi][ni][r2];
                }
            }
    }
}

// ====== k_p8 v6 (FROZEN): R3-v2 schedule + chunk swizzle, 59.6us measured ===
#define KP_NT 24
#define STGA4(tt, j) do {                                                      \
    __builtin_amdgcn_global_load_lds(                                          \
        (const __attribute__((address_space(1))) void*)(gA + (size_t)(j)*128*2304 + (size_t)(tt)*32), \
        (__attribute__((address_space(3))) void*)&Atile[(tt)&3][((j)*128 + (w<<4))*32], 16, 0, 0); \
} while (0)
#define STGB4(tt, j) do {                                                      \
    __builtin_amdgcn_global_load_lds(                                          \
        (const __attribute__((address_space(1))) void*)(gB + (size_t)(j)*128*2304 + (size_t)(tt)*32), \
        (__attribute__((address_space(3))) void*)&Btile[(tt)&3][((j)*128 + (w<<4))*32], 16, 0, 0); \
} while (0)

#define MFMA_B(a, b, c) __builtin_amdgcn_mfma_f32_16x16x32_bf16(a, b, c, 0, 0, 0)

#define KT_BODY(kt, BVU, BVF) do {                                             \
    const unsigned short* At = &Atile[(kt) & 3][0];                            \
    /* ---- E(kt) ---- */                                                      \
    __builtin_amdgcn_s_barrier();                                              \
    _Pragma("unroll")                                                          \
    for (int i = 0; i < 4; i++)                                                \
        af1[i] = *(const bf16x8*)&At[aOff + 2048 + i*512];                     \
    if ((kt) + 3 < KP_NT) { STGA4((kt)+3, 0); STGA4((kt)+3, 1); }              \
    __builtin_amdgcn_s_setprio(1);                                             \
    _Pragma("unroll")                                                          \
    for (int mi = 0; mi < 4; mi++)                                             \
        _Pragma("unroll")                                                      \
        for (int ni = 0; ni < 4; ni++)                                         \
            acc[mi][ni] = MFMA_B(af0[mi], BVU[ni], acc[mi][ni]);               \
    __builtin_amdgcn_s_setprio(0);                                             \
    /* ---- L(kt) ---- */                                                      \
    __builtin_amdgcn_s_barrier();                                              \
    if ((kt) < KP_NT-1) {                                                      \
        if ((kt) <= KP_NT-4)      asm volatile("s_waitcnt vmcnt(6)" ::: "memory"); \
        else if ((kt) == KP_NT-3) asm volatile("s_waitcnt vmcnt(4)" ::: "memory"); \
        else                      asm volatile("s_waitcnt vmcnt(0)" ::: "memory"); \
        __builtin_amdgcn_sched_barrier(0);                                     \
        const unsigned short* An = &Atile[((kt)+1) & 3][0];                    \
        const unsigned short* Bn = &Btile[((kt)+1) & 3][0];                    \
        _Pragma("unroll")                                                      \
        for (int i = 0; i < 4; i++)                                            \
            af0[i] = *(const bf16x8*)&An[aOff + i*512];                        \
        _Pragma("unroll")                                                      \
        for (int ni = 0; ni < 4; ni++)                                         \
            BVF[ni] = *(const bf16x8*)&Bn[bOff + ni*512];                      \
    }                                                                          \
    if ((kt) + 3 < KP_NT) { STGB4((kt)+3, 0); STGB4((kt)+3, 1); }              \
    __builtin_amdgcn_s_setprio(1);                                             \
    _Pragma("unroll")                                                          \
    for (int mi = 0; mi < 4; mi++)                                             \
        _Pragma("unroll")                                                      \
        for (int ni = 0; ni < 4; ni++)                                         \
            acc[4+mi][ni] = MFMA_B(af1[mi], BVU[ni], acc[4+mi][ni]);           \
    __builtin_amdgcn_s_setprio(0);                                             \
} while (0)

__global__ __launch_bounds__(512, 2) void k_p8(
    const unsigned short* __restrict__ A,   // Ybf: [bi][2304][2304] bf16
    const unsigned short* __restrict__ B,   // Rt : [bi][1024][2304] bf16
    unsigned short* __restrict__ C,         // partials: ks*psize + bi*2304*1024
    size_t psize)
{
    __shared__ unsigned short Atile[4][8192];   // 4 x 256 x 32 (16 KiB each)
    __shared__ unsigned short Btile[4][8192];

    // bijective XCD swizzle (m204, any nwg)
    int flat = blockIdx.x + gridDim.x*(blockIdx.y + gridDim.y*blockIdx.z);
    int nwg = gridDim.x*gridDim.y*gridDim.z;
    int qq = nwg >> 3, rr8 = nwg & 7;
    int xcd = flat & 7, sub = flat >> 3;
    int g = (xcd < rr8 ? xcd*(qq+1) : rr8*(qq+1) + (xcd - rr8)*qq) + sub;
    int nxy = gridDim.x*gridDim.y;              // 36
    int z = g / nxy; int rg = g - z*nxy;
    int by = rg / gridDim.x; int bx = rg - by*gridDim.x;

    int ks = z % 3, bi = z / 3;
    int kbase = ks * 768;
    int m0 = by * 256, n0 = bx * 256;
    const unsigned short* Ab = A + (size_t)bi * (2304ull*2304);
    const unsigned short* Bb = B + (size_t)bi * (1024ull*2304);

    int t = threadIdx.x;
    int w = t >> 6, lane = t & 63;
    int wr = w >> 2, wc = w & 3;
    int l15 = lane & 15, quad = lane >> 4;

    // staging source: row = t>>2, phys chunk (t&3) holds global chunk
    // (t&3) ^ ((row>>1)&3) = (t&3) ^ ((t>>3)&3)   (pre-swizzled global, G21)
    int scol = ((t & 3) ^ ((t >> 3) & 3))*8;
    const unsigned short* gA = Ab + (size_t)(m0 + (t >> 2))*2304 + kbase + scol;
    const unsigned short* gB = Bb + (size_t)(n0 + (t >> 2))*2304 + kbase + scol;

    // frag read offsets (elements): row*32 + (quad ^ ((row>>1)&3))*8
    int csw = (quad ^ ((l15 >> 1) & 3))*8;
    int aOff = (wr*128 + l15)*32 + csw;
    int bOff = (wc*64  + l15)*32 + csw;

    f32x4 acc[8][4];
    #pragma unroll
    for (int mi = 0; mi < 8; mi++)
        #pragma unroll
        for (int ni = 0; ni < 4; ni++) acc[mi][ni] = (f32x4){0.f,0.f,0.f,0.f};

    // prologue: stage tiles 0,1,2 (12 ops); tile0 ready at vmcnt(8)
    #pragma unroll
    for (int tt = 0; tt < 3; tt++) {
        STGA4(tt, 0); STGA4(tt, 1);
        STGB4(tt, 0); STGB4(tt, 1);
    }
    asm volatile("s_waitcnt vmcnt(8)" ::: "memory");
    __builtin_amdgcn_s_barrier();

    bf16x8 af0[4], af1[4], bvA[4], bvB[4];
    // S1(0): af0 + bvA from buf0
    #pragma unroll
    for (int i = 0; i < 4; i++)
        af0[i] = *(const bf16x8*)&Atile[0][aOff + i*512];
    #pragma unroll
    for (int ni = 0; ni < 4; ni++)
        bvA[ni] = *(const bf16x8*)&Btile[0][bOff + ni*512];

    #pragma unroll 1
    for (int ktp = 0; ktp < KP_NT/2; ktp++) {
        int kt0 = ktp*2;
        KT_BODY(kt0,     bvA, bvB);   // even tile: use bvA, fill bvB
        KT_BODY(kt0 + 1, bvB, bvA);   // odd tile:  use bvB, fill bvA
    }

    // epilogue: bf16 partial write
    unsigned short* Cb = C + (size_t)ks*psize + (size_t)bi*(2304ull*1024);
    #pragma unroll
    for (int mi = 0; mi < 8; mi++)
        #pragma unroll
        for (int ni = 0; ni < 4; ni++) {
            int col = n0 + wc*64 + ni*16 + l15;
            int rowb = m0 + wr*128 + mi*16 + quad*4;
            #pragma unroll
            for (int r = 0; r < 4; r++)
                Cb[(size_t)(rowb + r)*1024 + col] = f2bf(acc[mi][ni][r]);
        }
}

// ------ K3b v4 (R8 best): y-diag 3-tap * rnrm + fuse1, fp16, 8 rows/block ---
__global__ __launch_bounds__(256) void k_fuse_a2(const unsigned short* __restrict__ T,
    const float* __restrict__ rnrm, const float* __restrict__ fw,
    unsigned short* __restrict__ Y1)
{
    __shared__ float Sl[10][280];
    int flat = blockIdx.x + 9*(blockIdx.y + 288*blockIdx.z);
    int nwg = 2592*gridDim.z;          // %8 == 0 for nb in {1,2,4}
    int cpx = nwg >> 3;
    int g = (flat & 7)*cpx + (flat >> 3);
    int bi = g / 2592; int rem = g - bi*2592;
    int by = rem / 9;  int qt = rem - by*9;

    int p0 = by*8, q0 = qt*256;
    const unsigned short* Tb = T + (size_t)bi*KL*KL;
    const float* rn = rnrm + bi*KL;
    int t = threadIdx.x;
    bool edge = (qt == 0) | (qt == 8);
    if (!edge) {
        for (int idx = t; idx < 10*34; idx += 256) {
            int r = idx / 34, j = idx - r*34;
            int pp = p0 - 1 + r;
            int qq0 = q0 - 8 + j*8;
            float s[8];
            #pragma unroll
            for (int k = 0; k < 8; k++) s[k] = 0.f;
            if ((unsigned)pp < KL) {
                size_t base = (size_t)pp*KL + qq0;
                bool bm = (pp >= KHS), bp = (pp < KL - KHS);
                size_t offm = bm ? (size_t)OFFY : 0;
                size_t offp = bp ? (size_t)OFFY : 0;
                float fm = bm ? 1.f : 0.f, fp2 = bp ? 1.f : 0.f;
                f16x8 v0 = *(const f16x8*)&Tb[base];
                f16x8 vm = *(const f16x8*)&Tb[base - offm];
                f16x8 vp = *(const f16x8*)&Tb[base + offp];
                #pragma unroll
                for (int k = 0; k < 8; k++)
                    s[k] = ((float)v0[k] + fm*(float)vm[k] + fp2*(float)vp[k]) * rn[qq0 + k];
            }
            #pragma unroll
            for (int k = 0; k < 8; k++) Sl[r][j*8 + k] = s[k];
        }
    } else {
        for (int idx = t; idx < 10*272; idx += 256) {
            int r = idx / 272, c = idx - r*272;
            int pp = p0 - 1 + r, qq = q0 - 8 + c;
            float s = 0.f;
            if ((unsigned)pp < KL && (unsigned)qq < KL) {
                size_t base = (size_t)pp*KL + qq;
                float acc = h2f(Tb[base]);
                if (pp >= KHS && qq >= KHS)         acc += h2f(Tb[base - OFFY]);
                if (pp < KL - KHS && qq < KL - KHS) acc += h2f(Tb[base + OFFY]);
                s = acc * rn[qq];
            }
            Sl[r][c] = s;
        }
    }
    __syncthreads();
    float w[9];
    #pragma unroll
    for (int i = 0; i < 9; i++) w[i] = fw[i];
    int q = q0 + t;
    float h0[10], h1[10], h2[10];
    #pragma unroll
    for (int r = 0; r < 10; r++) {
        float s0 = Sl[r][t+7], s1 = Sl[r][t+8], s2 = Sl[r][t+9];
        h0[r] = w[0]*s0 + w[1]*s1 + w[2]*s2;
        h1[r] = w[3]*s0 + w[4]*s1 + w[5]*s2;
        h2[r] = w[6]*s0 + w[7]*s1 + w[8]*s2;
    }
    #pragma unroll
    for (int rr = 0; rr < 8; rr++) {
        Y1[((size_t)bi*KL + p0 + rr)*KL + q] = f2h(h0[rr] + h1[rr+1] + h2[rr+2]);
    }
}

// ------ K5 v6 (R8 best): fuse conv #2 + softmax -> bf16; 4 rows/block -------
__global__ __launch_bounds__(256) void k_fuse_b(const unsigned short* __restrict__ Y1,
    const float* __restrict__ fw, const float* __restrict__ mm,
    unsigned short* __restrict__ Ybf)
{
    __shared__ float rowb[6][KL];   // 55296 B
    int blk = blockIdx.x;           // nb*576
    int tp0 = (blk % 576)*4;
    int bi  = blk / 576;
    int t = threadIdx.x;
    const unsigned short* Yb = Y1 + (size_t)bi*KL*KL;
    for (int idx = t; idx < 6*(KL/8); idx += 256) {
        int a = idx / (KL/8), i = idx - a*(KL/8);
        int t2 = tp0 - 1 + a;
        if ((unsigned)t2 < KL) {
            int pr = (t2 % KHS)*KHS + t2/KHS;
            f16x8 v = *(const f16x8*)&Yb[(size_t)pr*KL + i*8];
            #pragma unroll
            for (int j = 0; j < 8; j++) rowb[a][i*8 + j] = (float)v[j];
        } else {
            #pragma unroll
            for (int j = 0; j < 8; j++) rowb[a][i*8 + j] = 0.f;
        }
    }
    float w9[9];
    #pragma unroll
    for (int i = 0; i < 9; i++) w9[i] = fw[i];
    __syncthreads();
    int w = t >> 6, lane = t & 63;
    int tp = tp0 + w;
    int x = tp / KHS, y = tp - x*KHS;   // tp = x*48 + y
    int p = y*KHS + x;
    const float* mmb = mm + bi*KL;
    float vals[36];
    float lmax = -1e30f;
    #pragma unroll
    for (int i = 0; i < 36; i++) {
        int q = lane + i*64;
        int qm = (q >= KHS)      ? q - KHS : 2255 + q;
        int qp = (q <= KL-1-KHS) ? q + KHS : q - 2255;
        float fm = (q != 0)    ? 1.f : 0.f;
        float fp = (q != KL-1) ? 1.f : 0.f;
        float am = w9[0]*rowb[w][qm] + w9[3]*rowb[w+1][qm] + w9[6]*rowb[w+2][qm];
        float a0 = w9[1]*rowb[w][q]  + w9[4]*rowb[w+1][q]  + w9[7]*rowb[w+2][q];
        float ap = w9[2]*rowb[w][qp] + w9[5]*rowb[w+1][qp] + w9[8]*rowb[w+2][qp];
        float val = (fm*am + a0 + fp*ap) * mmb[q] * 10.0f;
        vals[i] = val;
        lmax = fmaxf(lmax, val);
    }
    #pragma unroll
    for (int off = 32; off > 0; off >>= 1) lmax = fmaxf(lmax, __shfl_down(lmax, off));
    lmax = __shfl(lmax, 0);
    float lsum = 0.f;
    #pragma unroll
    for (int i = 0; i < 36; i++) {
        float e = __expf(vals[i] - lmax);
        vals[i] = e;
        lsum += e;
    }
    #pragma unroll
    for (int off = 32; off > 0; off >>= 1) lsum += __shfl_down(lsum, off);
    lsum = __shfl(lsum, 0);
    float inv = 1.0f / lsum;
    unsigned short* orow = Ybf + ((size_t)bi*KL + p)*KL;
    #pragma unroll
    for (int i = 0; i < 36; i++) {
        int q = lane + i*64;
        orow[q] = f2bf(vals[i]*inv*mmb[q]);
    }
}

// ---- KR v2: Rt[n][k] bf16 via LDS transpose (coalesced reads + writes) -----
__global__ __launch_bounds__(256) void k_buildRt(const float* __restrict__ bsrc,
    unsigned short* __restrict__ Rt)
{
    __shared__ unsigned short Ls[2][48][65];
    int blk = blockIdx.x;             // nb*384: vb fastest, then jj, then bi
    int vb = blk % 24;
    int jj = (blk / 24) % 16;
    int bi = blk / 384;
    int ky = jj >> 2, kx = jj & 3;
    int v0 = vb*2;
    int t = threadIdx.x;
    int c = t & 63, u4 = t >> 6;

    #pragma unroll
    for (int vv = 0; vv < 2; vv++) {
        int ry = 2*(v0 + vv) + ky - 1;
        bool ryok = (unsigned)ry < KHH;
        const float* brow = bsrc + (((size_t)bi*KHH + (ryok ? ry : 0))*KHH)*KC;
        #pragma unroll
        for (int j = 0; j < 12; j++) {
            int u = u4*12 + j;
            int rx = 2*u + kx - 1;
            float val = 0.f;
            if (ryok && (unsigned)rx < KHH)
                val = brow[(size_t)rx*KC + c];
            Ls[vv][u][c] = f2bf(val);
        }
    }
    __syncthreads();

    int cn = t >> 2, part = t & 3;
    unsigned short* orow = Rt + ((size_t)bi*1024 + jj*64 + cn)*KL + vb*96;
    #pragma unroll
    for (int ch = 0; ch < 3; ch++) {
        int ql = part*24 + ch*8;          // 8-aligned, never straddles vv
        int vv = ql / 48;
        int ub = ql - vv*48;
        bf16x8 v8;
        #pragma unroll
        for (int j = 0; j < 8; j++)
            v8[j] = (short)Ls[vv][ub + j][cn];
        *(bf16x8*)&orow[ql] = v8;
    }
}

// -- K8 v2: overlap-add over 3 bf16 partials, 8 ch/thread, bf16x8 loads ------
__global__ __launch_bounds__(256) void k_overlap(const unsigned short* __restrict__ P,
    float* __restrict__ out, size_t psize)
{
    size_t gid = (size_t)blockIdx.x*256 + threadIdx.x;   // nb*96*96*8
    int c8 = (int)(gid & 7)*8;
    size_t r = gid >> 3;
    int ix = (int)(r % KHH); r /= KHH;
    int iy = (int)(r % KHH);
    int bi = (int)(r / KHH);
    float acc[8];
    #pragma unroll
    for (int j = 0; j < 8; j++) acc[j] = 0.f;
    #pragma unroll
    for (int sy = 0; sy < 2; sy++) {
        int ky = (iy & 1) ? (sy*2) : (sy*2 + 1);
        int yp = (iy + 1 - ky) >> 1;
        if ((unsigned)yp >= KHS) continue;
        #pragma unroll
        for (int sx = 0; sx < 2; sx++) {
            int kx = (ix & 1) ? (sx*2) : (sx*2 + 1);
            int xp = (ix + 1 - kx) >> 1;
            if ((unsigned)xp >= KHS) continue;
            size_t idx = (((size_t)bi*KL + yp*KHS + xp)*16 + (ky*4 + kx))*64 + c8;
            #pragma unroll
            for (int s = 0; s < 3; s++) {
                bf16x8 v = *(const bf16x8*)&P[idx + s*psize];
                #pragma unroll
                for (int j = 0; j < 8; j++)
                    acc[j] += bf2f((unsigned short)v[j]);
            }
        }
    }
    float* op = &out[(((size_t)bi*KHH + iy)*KHH + ix)*KC + c8];
    f32x4 o0 = (f32x4){acc[0], acc[1], acc[2], acc[3]} * 0.25f;
    f32x4 o1 = (f32x4){acc[4], acc[5], acc[6], acc[7]} * 0.25f;
    *(f32x4*)&op[0] = o0;
    *(f32x4*)&op[4] = o1;
}

extern "C" void kernel_launch(void* const* d_in, const int* in_sizes, int n_in,
                              void* d_out, int out_size, void* d_ws, size_t ws_size,
                              hipStream_t stream)
{
    const float* f    = (const float*)d_in[0];
    const float* b    = (const float*)d_in[1];
    const float* mask = (const float*)d_in[2];
    const float* fw   = (const float*)d_in[3];
    float* out = (float*)d_out;

    auto need = [](int nbc) -> size_t {
        return (size_t)nbc * (2ull*KL*KC + 4ull*KL + 2ull*(size_t)KL*KL) * 4ull;
    };
    int nbc = 4;
    if (need(nbc) > ws_size) nbc = 2;
    if (need(nbc) > ws_size) nbc = 1;

    for (int bi0 = 0; bi0 < 4; bi0 += nbc) {
        int nb = (4 - bi0 < nbc) ? (4 - bi0) : nbc;
        const float* fc = f    + (size_t)bi0*KHH*KHH*KC;
        const float* bc = b    + (size_t)bi0*KHH*KHH*KC;
        const float* mc = mask + (size_t)bi0*KHH*KHH;
        float* outc = out + (size_t)bi0*KHH*KHH*KC;

        float* w    = (float*)d_ws;
        float* nbuf = w;  w += (size_t)nbc*KL;
        float* mdd  = w;  w += (size_t)nbc*KL;
        float* rnrm = w;  w += (size_t)nbc*KL;
        float* mmb  = w;  w += (size_t)nbc*KL;
        float* bufA = w;  w += (size_t)nbc*KL*KL;
        float* bufB = w;
        // lifetimes:
        //  bufB: [Ahat|Bhat] (fp16) -> Y1 (fp16) -> P0..P2 (bf16, 3 partials)
        //  bufA: T (fp16) -> [Ybf bf16 | Rt bf16]
        unsigned short* Ahat = (unsigned short*)bufB;
        unsigned short* Bhat = Ahat + (size_t)nbc*KL*192;
        unsigned short* Tbuf = (unsigned short*)bufA;
        unsigned short* Y1   = (unsigned short*)bufB;
        unsigned short* Ybf = (unsigned short*)bufA;
        unsigned short* Rtb = Ybf + (size_t)nbc*KL*KL;
        unsigned short* Pbuf = (unsigned short*)bufB;
        size_t psize = (size_t)nbc*KL*1024;   // one split-K partial (elements)

        k_prep2     <<<nb*KL/4, 256, 0, stream>>>(fc, bc, mc, nbuf, mdd, Ahat, Bhat);
        k_normmask  <<<(nb*KL)/256, 256, 0, stream>>>(nbuf, mdd, rnrm, mmb);
        // T = Ahat * Bhat^T  (K=192 fp16 single-segment, fp16 out)
        k_mfma_bt<6,2,true><<<dim3(18, 18, nb), 256, 0, stream>>>(
            Ahat, Bhat, Tbuf, KL, (size_t)KL*192, (size_t)KL*192, (size_t)KL*KL,
            192, 1, 0);
        // y-diag 3-tap * rnrm + fuse1: T fp16 (bufA) -> Y1 fp16 (bufB)
        k_fuse_a2   <<<dim3(9, 288, nb), 256, 0, stream>>>(Tbuf, rnrm, fw, Y1);
        // fuse2 + softmax: Y1 fp16 (bufB) -> Ybf bf16 (bufA)
        k_fuse_b    <<<nb*576, 256, 0, stream>>>(Y1, fw, mmb, Ybf);
        // Rt build via LDS transpose (coalesced)
        k_buildRt   <<<nb*384, 256, 0, stream>>>(bc, Rtb);
        // P = Ybf * Rt^T (K=2304 bf16, split-K=3, bf16 partials P0..P2) [FROZEN]
        k_p8<<<dim3(4, 9, nb*3), 512, 0, stream>>>(Ybf, Rtb, Pbuf, psize);
        // overlap-add, 8 channels/thread
        k_overlap   <<<nb*288, 256, 0, stream>>>(Pbuf, outc, psize);
    }
}